// Round 3
// baseline (281.842 us; speedup 1.0000x reference)
//
#include <hip/hip_runtime.h>
#include <hip/hip_bf16.h>
#include <stdint.h>

// Problem constants (fixed by the reference)
#define NTOK 4096
#define HID  512
#define INSZ 1024   // E + H
#define KIN  1536   // INSZ + HID (fused LSTM input: x | h)
#define KCAT 64
#define CCH  128
#define MCELL 4
#define G4H  2048   // 4*H

typedef unsigned short u16;
typedef __bf16 bf16x8 __attribute__((ext_vector_type(8)));
typedef float  f32x4  __attribute__((ext_vector_type(4)));

__device__ __forceinline__ u16 f2bf(float f) {
    unsigned u = __float_as_uint(f);
    u += 0x7fffu + ((u >> 16) & 1u);   // RTNE
    return (u16)(u >> 16);
}
__device__ __forceinline__ float bf2f(u16 v) {
    return __uint_as_float(((unsigned)v) << 16);
}
__device__ __forceinline__ void store_bf4(u16* p, float4 v) {
    ushort4 r;
    r.x = f2bf(v.x); r.y = f2bf(v.y); r.z = f2bf(v.z); r.w = f2bf(v.w);
    *reinterpret_cast<ushort4*>(p) = r;
}
__device__ __forceinline__ void gl16(const u16* g, u16* l) {
    __builtin_amdgcn_global_load_lds((const __attribute__((address_space(1))) void*)g,
                                     (__attribute__((address_space(3))) void*)l, 16, 0, 0);
}

// meta layout (ints): [0..3] ci padded cnt, [4..7] ci padded off,
//                     [8..71] cat padded cnt, [72..135] cat padded off
// ---------------------------------------------------------------------------
// Kernel 1: bucket tokens by ci (pad 128) and by cat (pad 64).
// ---------------------------------------------------------------------------
__global__ __launch_bounds__(1024) void build_perm(
    const int* __restrict__ ci, const int* __restrict__ cat,
    int* __restrict__ meta, int* __restrict__ perm_ci,
    int* __restrict__ inv_ci, int* __restrict__ perm_cat)
{
    __shared__ int cnt_ci[MCELL], cur_ci[MCELL];
    __shared__ int cnt_cat[KCAT], cur_cat[KCAT];
    int tid = threadIdx.x;
    if (tid < MCELL) cnt_ci[tid] = 0;
    if (tid < KCAT)  cnt_cat[tid] = 0;
    __syncthreads();
    for (int t = tid; t < NTOK; t += 1024) {
        atomicAdd(&cnt_ci[ci[t]], 1);
        atomicAdd(&cnt_cat[cat[t]], 1);
    }
    __syncthreads();
    if (tid == 0) {
        int off = 0;
        for (int m = 0; m < MCELL; ++m) {
            int p = (cnt_ci[m] + 127) & ~127;
            meta[m] = p; meta[4 + m] = off; cur_ci[m] = off; off += p;
        }
        off = 0;
        for (int k = 0; k < KCAT; ++k) {
            int p = (cnt_cat[k] + 63) & ~63;
            meta[8 + k] = p; meta[72 + k] = off; cur_cat[k] = off; off += p;
        }
    }
    __syncthreads();
    for (int i = tid; i < 4608; i += 1024) perm_ci[i] = -1;
    for (int i = tid; i < 8192; i += 1024) perm_cat[i] = -1;
    __syncthreads();
    for (int t = tid; t < NTOK; t += 1024) {
        int s = atomicAdd(&cur_ci[ci[t]], 1);
        perm_ci[s] = t; inv_ci[t] = s;
        int sc = atomicAdd(&cur_cat[cat[t]], 1);
        perm_cat[sc] = t;
    }
}

// ---------------------------------------------------------------------------
// Kernel 2: fused packs — A_pack (slot-ordered x|h), Wb (W_ih|W_hh), Wlin.
// All bf16, all row-per-block-ish with 192 threads (1536 elems / block).
// ---------------------------------------------------------------------------
__global__ __launch_bounds__(192) void pack_all(
    const float* __restrict__ x, const float* __restrict__ h,
    const float* __restrict__ Wih, const float* __restrict__ Whh,
    const float* __restrict__ W_lin,
    const int* __restrict__ perm_ci,
    u16* __restrict__ A_pack, u16* __restrict__ Wb, u16* __restrict__ Wlin)
{
    int b = blockIdx.x;
    int c = threadIdx.x * 8;
    if (b < 4608) {                       // A_pack row (ci slot)
        int t = perm_ci[b];
        u16* dst = A_pack + (size_t)b * KIN + c;
        if (t < 0) {
            *reinterpret_cast<int4*>(dst) = make_int4(0, 0, 0, 0);
            return;
        }
        const float* src = (c < INSZ) ? (x + (size_t)t * INSZ + c)
                                      : (h + (size_t)t * HID + (c - INSZ));
        store_bf4(dst, *(const float4*)src);
        store_bf4(dst + 4, *(const float4*)(src + 4));
    } else if (b < 4608 + 8192) {         // Wb row (m*2048+j)
        int row = b - 4608;
        int m = row >> 11, j = row & 2047;
        const float* src = (c < INSZ) ? (Wih + ((size_t)m * G4H + j) * INSZ + c)
                                      : (Whh + ((size_t)m * G4H + j) * HID + (c - INSZ));
        u16* dst = Wb + (size_t)row * KIN + c;
        store_bf4(dst, *(const float4*)src);
        store_bf4(dst + 4, *(const float4*)(src + 4));
    } else {                              // Wlin: 3 rows of 512 per block
        int base = (b - (4608 + 8192)) * 3;
        int row = base + (c >> 9);
        int col = c & 511;
        if (row >= KCAT * CCH) return;
        const float* src = W_lin + (size_t)row * HID + col;
        u16* dst = Wlin + (size_t)row * HID + col;
        store_bf4(dst, *(const float4*)src);
        store_bf4(dst + 4, *(const float4*)(src + 4));
    }
}

// ---------------------------------------------------------------------------
// Kernel 3: fused GEMMs.
//  z<4 : gates GEMM, 128x64 tile, BK=32, gl16 staging (3 calls/wave/iter).
//  z==4: log_odds GEMM, 64x128 tile, K=512; B (Wlin) via gl16, A via VALU.
// XOR k-chunk swizzle on the source side -> ds_read_b128 conflict-free
// (validated round 2: SQ_LDS_BANK_CONFLICT == 0).
// ---------------------------------------------------------------------------
__global__ __launch_bounds__(256, 4) void mega_gemm(
    const u16* __restrict__ A_pack,   // [4608][1536]
    const u16* __restrict__ Wb,       // [4][2048][1536]
    const u16* __restrict__ Wlin,     // [64][128][512]
    const float* __restrict__ et,     // [N,512] f32
    const float* __restrict__ b_lin,  // [64,128]
    const int* __restrict__ meta,
    const int* __restrict__ perm_cat,
    u16* __restrict__ gates,          // [4608][2048] bf16
    float* __restrict__ out)          // log_odds at out[0..N*128)
{
    __shared__ __align__(16) u16 As[128 * 32];   // 8 KB
    __shared__ __align__(16) u16 Bs[64 * 32];    // 4 KB
    __shared__ int srow[64];

    int tid = threadIdx.x;
    int lane = tid & 63, wave = tid >> 6;
    int r0 = tid >> 2, cb = tid & 3;
    int kcb = cb ^ ((r0 >> 1) & 3);              // source k-chunk (swizzle)
    int qd = lane >> 4, l15 = lane & 15;
    int qs = (qd ^ ((l15 >> 1) & 3)) * 8;        // frag-read k-chunk (u16)

    if (blockIdx.z < 4) {
        // ---------------- gates GEMM ----------------
        int m = blockIdx.z, rt = blockIdx.x, ct = blockIdx.y;
        int pcnt = meta[m];
        if (rt * 128 >= pcnt) return;
        int row0 = meta[4 + m] + rt * 128;

        const u16* gA0 = A_pack + (size_t)(row0 + r0) * KIN + kcb * 8;
        const u16* gA1 = gA0 + (size_t)64 * KIN;
        const u16* gB0 = Wb + ((size_t)m * G4H + ct * 64 + r0) * KIN + kcb * 8;
        u16* lA0 = As + wave * 512;
        u16* lA1 = As + 2048 + wave * 512;
        u16* lB0 = Bs + wave * 512;

        int wr = wave >> 1, wc = wave & 1;

        f32x4 acc[4][2];
        #pragma unroll
        for (int i = 0; i < 4; ++i) {
            acc[i][0] = (f32x4){0.f, 0.f, 0.f, 0.f};
            acc[i][1] = (f32x4){0.f, 0.f, 0.f, 0.f};
        }

        for (int ks = 0; ks < KIN / 32; ++ks) {
            gl16(gA0, lA0); gl16(gA1, lA1); gl16(gB0, lB0);
            gA0 += 32; gA1 += 32; gB0 += 32;
            __syncthreads();
            bf16x8 fa[4], fb[2];
            #pragma unroll
            for (int ti = 0; ti < 4; ++ti)
                fa[ti] = *reinterpret_cast<const bf16x8*>(&As[(wr * 64 + ti * 16 + l15) * 32 + qs]);
            #pragma unroll
            for (int tj = 0; tj < 2; ++tj)
                fb[tj] = *reinterpret_cast<const bf16x8*>(&Bs[(wc * 32 + tj * 16 + l15) * 32 + qs]);
            #pragma unroll
            for (int ti = 0; ti < 4; ++ti)
                #pragma unroll
                for (int tj = 0; tj < 2; ++tj)
                    acc[ti][tj] = __builtin_amdgcn_mfma_f32_16x16x32_bf16(fa[ti], fb[tj], acc[ti][tj], 0, 0, 0);
            __syncthreads();
        }

        #pragma unroll
        for (int ti = 0; ti < 4; ++ti) {
            #pragma unroll
            for (int tj = 0; tj < 2; ++tj) {
                int gcol = ct * 64 + wc * 32 + tj * 16 + l15;
                #pragma unroll
                for (int r = 0; r < 4; ++r) {
                    int grow = row0 + wr * 64 + ti * 16 + qd * 4 + r;
                    gates[(size_t)grow * G4H + gcol] = f2bf(acc[ti][tj][r]);
                }
            }
        }
    } else {
        // ---------------- log_odds GEMM ----------------
        int id = blockIdx.y * 36 + blockIdx.x;   // [0,1152)
        int k = id >> 4, rtl = id & 15;
        if (k >= KCAT) return;
        int pcnt = meta[8 + k];
        if (rtl * 64 >= pcnt) return;
        int base = meta[72 + k] + rtl * 64;

        if (tid < 64) srow[tid] = perm_cat[base + tid];
        __syncthreads();

        const u16* gW0 = Wlin + ((size_t)k * CCH + r0) * HID + kcb * 8;
        const u16* gW1 = gW0 + (size_t)64 * HID;
        u16* lW0 = As + wave * 512;
        u16* lW1 = As + 2048 + wave * 512;

        int trow = srow[r0];
        u16* adst = &Bs[r0 * 32 + (cb ^ ((r0 >> 1) & 3)) * 8];
        const float* asrc = (trow >= 0) ? (et + (size_t)trow * HID + cb * 8) : nullptr;

        f32x4 acc[4][2];
        #pragma unroll
        for (int i = 0; i < 4; ++i) {
            acc[i][0] = (f32x4){0.f, 0.f, 0.f, 0.f};
            acc[i][1] = (f32x4){0.f, 0.f, 0.f, 0.f};
        }

        for (int kk = 0; kk < HID; kk += 32) {
            gl16(gW0, lW0); gl16(gW1, lW1);
            gW0 += 32; gW1 += 32;
            if (asrc) {
                store_bf4(adst,     *(const float4*)(asrc + kk));
                store_bf4(adst + 4, *(const float4*)(asrc + kk + 4));
            } else {
                *reinterpret_cast<int4*>(adst) = make_int4(0, 0, 0, 0);
            }
            __syncthreads();
            bf16x8 fa[4], fb[2];
            #pragma unroll
            for (int ti = 0; ti < 4; ++ti)
                fa[ti] = *reinterpret_cast<const bf16x8*>(&Bs[(ti * 16 + l15) * 32 + qs]);
            #pragma unroll
            for (int tj = 0; tj < 2; ++tj)
                fb[tj] = *reinterpret_cast<const bf16x8*>(&As[(wave * 32 + tj * 16 + l15) * 32 + qs]);
            #pragma unroll
            for (int ti = 0; ti < 4; ++ti)
                #pragma unroll
                for (int tj = 0; tj < 2; ++tj)
                    acc[ti][tj] = __builtin_amdgcn_mfma_f32_16x16x32_bf16(fa[ti], fb[tj], acc[ti][tj], 0, 0, 0);
            __syncthreads();
        }

        #pragma unroll
        for (int ti = 0; ti < 4; ++ti) {
            #pragma unroll
            for (int tj = 0; tj < 2; ++tj) {
                int n = wave * 32 + tj * 16 + l15;
                #pragma unroll
                for (int r = 0; r < 4; ++r) {
                    int row = ti * 16 + qd * 4 + r;
                    int t = srow[row];
                    if (t >= 0)
                        out[(size_t)t * CCH + n] = acc[ti][tj][r] + b_lin[k * CCH + n];
                }
            }
        }
    }
}

// ---------------------------------------------------------------------------
// Kernel 4: LSTM pointwise epilogue (token-indexed via inverse slot map).
// ---------------------------------------------------------------------------
__global__ __launch_bounds__(256) void lstm_epilogue(
    const u16* __restrict__ gates,    // [4608][2048] bf16, slot order
    const int* __restrict__ meta,
    const int* __restrict__ inv_ci,
    const float* __restrict__ c,
    const float* __restrict__ b_ih,   // [4,2048]
    const float* __restrict__ b_hh,   // [4,2048]
    float* __restrict__ out)
{
    int idx = blockIdx.x * 256 + threadIdx.x;   // [0, N*512)
    int t = idx >> 9;
    int hh = idx & 511;
    int s = inv_ci[t];
    int m = (s >= meta[5]) + (s >= meta[6]) + (s >= meta[7]);

    const u16* g = gates + (size_t)s * G4H;
    const float* bi = b_ih + (size_t)m * G4H;
    const float* bh = b_hh + (size_t)m * G4H;
    float gi = bf2f(g[hh])        + bi[hh]        + bh[hh];
    float gf = bf2f(g[512 + hh])  + bi[512 + hh]  + bh[512 + hh];
    float gg = bf2f(g[1024 + hh]) + bi[1024 + hh] + bh[1024 + hh];
    float go = bf2f(g[1536 + hh]) + bi[1536 + hh] + bh[1536 + hh];

    float si = 1.f / (1.f + __expf(-gi));
    float sf = 1.f / (1.f + __expf(-gf));
    float so = 1.f / (1.f + __expf(-go));
    float ct = c[(size_t)t * HID + hh];
    float c2 = sf * ct + si * tanhf(gg);
    float h2 = so * tanhf(c2);

    const size_t o_h2 = (size_t)NTOK * CCH;
    const size_t o_c2 = o_h2 + (size_t)NTOK * HID;
    out[o_h2 + (size_t)t * HID + hh] = h2;
    out[o_c2 + (size_t)t * HID + hh] = c2;
}

// ---------------------------------------------------------------------------
extern "C" void kernel_launch(void* const* d_in, const int* in_sizes, int n_in,
                              void* d_out, int out_size, void* d_ws, size_t ws_size,
                              hipStream_t stream) {
    const float* et    = (const float*)d_in[0];
    const float* x     = (const float*)d_in[1];
    const float* h     = (const float*)d_in[2];
    const float* c     = (const float*)d_in[3];
    const int*   cat   = (const int*)d_in[4];
    const int*   ci    = (const int*)d_in[5];
    const float* W_lin = (const float*)d_in[6];
    const float* b_lin = (const float*)d_in[7];
    const float* W_ih  = (const float*)d_in[8];
    const float* W_hh  = (const float*)d_in[9];
    const float* b_ih  = (const float*)d_in[10];
    const float* b_hh  = (const float*)d_in[11];
    float* out = (float*)d_out;

    char* ws = (char*)d_ws;
    int* meta     = (int*)ws;                       // 1 KB
    int* perm_ci  = (int*)(ws + 1024);              // 4608 ints
    int* inv_ci   = (int*)(ws + 19456);             // 4096 ints
    int* perm_cat = (int*)(ws + 35840);             // 8192 ints
    u16* A_pack   = (u16*)(ws + 68608);             // 4608*1536*2  = 14155776
    u16* Wb       = (u16*)(ws + 68608 + 14155776);  // 4*2048*1536*2 = 25165824
    u16* Wlin     = (u16*)(ws + 68608 + 14155776 + 25165824);           // 8388608
    u16* gates    = (u16*)(ws + 68608 + 14155776 + 25165824 + 8388608); // 18874368

    build_perm<<<1, 1024, 0, stream>>>(ci, cat, meta, perm_ci, inv_ci, perm_cat);

    pack_all<<<4608 + 8192 + 2731, 192, 0, stream>>>(
        x, h, W_ih, W_hh, W_lin, perm_ci, A_pack, Wb, Wlin);

    dim3 ggrid(36, 32, 5);   // z<4: gates (rt,ct); z==4: logodds (linearized)
    mega_gemm<<<ggrid, 256, 0, stream>>>(A_pack, Wb, Wlin, et, b_lin, meta,
                                         perm_cat, gates, out);

    lstm_epilogue<<<(NTOK * HID) / 256, 256, 0, stream>>>(gates, meta, inv_ci, c, b_ih, b_hh, out);
}